// Round 1
// baseline (1538.221 us; speedup 1.0000x reference)
//
#include <hip/hip_runtime.h>

typedef short short8 __attribute__((ext_vector_type(8)));
typedef float f32x4 __attribute__((ext_vector_type(4)));
typedef unsigned short ushort_t;

#define T_SEQ 2048
#define C_DIM 2048
#define H_NUM 16
#define D_HEAD 128
#define B_NUM 4
#define M_ROWS (B_NUM * T_SEQ)   // 8192

__device__ __forceinline__ unsigned short f2bf(float f) {
    union { float f; unsigned u; } v; v.f = f;
    unsigned r = v.u + 0x7FFFu + ((v.u >> 16) & 1u);
    return (unsigned short)(r >> 16);
}
__device__ __forceinline__ float bf2f(unsigned short u) {
    union { unsigned u; float f; } v; v.u = ((unsigned)u) << 16;
    return v.f;
}

// ---------------- weight cast + transpose: wt[w][n][k] = W_w[k][n] (bf16) ----
__global__ __launch_bounds__(256) void wcast_kernel(const float* __restrict__ W0,
                                                    const float* __restrict__ W1,
                                                    const float* __restrict__ W2,
                                                    const float* __restrict__ W3,
                                                    unsigned short* __restrict__ wt) {
    __shared__ float tile[32][33];
    const float* W = (blockIdx.z == 0) ? W0 : (blockIdx.z == 1) ? W1 : (blockIdx.z == 2) ? W2 : W3;
    unsigned short* out = wt + (size_t)blockIdx.z * C_DIM * C_DIM;
    int tx = threadIdx.x, ty = threadIdx.y;      // block (32, 8)
    int n0 = blockIdx.x * 32, k0 = blockIdx.y * 32;
    #pragma unroll
    for (int j = 0; j < 32; j += 8)
        tile[ty + j][tx] = W[(size_t)(k0 + ty + j) * C_DIM + n0 + tx];
    __syncthreads();
    #pragma unroll
    for (int j = 0; j < 32; j += 8)
        out[(size_t)(n0 + ty + j) * C_DIM + k0 + tx] = f2bf(tile[tx][ty + j]);
}

// ---------------- LayerNorm -> bf16 ----------------------------------------
__global__ __launch_bounds__(256) void ln_kernel(const float* __restrict__ x,
                                                 const float* __restrict__ g,
                                                 const float* __restrict__ bta,
                                                 unsigned short* __restrict__ nx) {
    int row = blockIdx.x;
    int tid = threadIdx.x;
    const float* xr = x + (size_t)row * C_DIM;
    float4 v0 = *(const float4*)(xr + tid * 8);
    float4 v1 = *(const float4*)(xr + tid * 8 + 4);
    float s = v0.x + v0.y + v0.z + v0.w + v1.x + v1.y + v1.z + v1.w;
    float q = v0.x * v0.x + v0.y * v0.y + v0.z * v0.z + v0.w * v0.w +
              v1.x * v1.x + v1.y * v1.y + v1.z * v1.z + v1.w * v1.w;
    #pragma unroll
    for (int m = 32; m; m >>= 1) { s += __shfl_xor(s, m); q += __shfl_xor(q, m); }
    __shared__ float red[2][4];
    int wave = tid >> 6, lane = tid & 63;
    if (lane == 0) { red[0][wave] = s; red[1][wave] = q; }
    __syncthreads();
    s = red[0][0] + red[0][1] + red[0][2] + red[0][3];
    q = red[1][0] + red[1][1] + red[1][2] + red[1][3];
    float mu = s * (1.0f / C_DIM);
    float var = q * (1.0f / C_DIM) - mu * mu;
    float rstd = rsqrtf(var + 1e-5f);
    float4 g0 = *(const float4*)(g + tid * 8);
    float4 g1 = *(const float4*)(g + tid * 8 + 4);
    float4 b0 = *(const float4*)(bta + tid * 8);
    float4 b1 = *(const float4*)(bta + tid * 8 + 4);
    unsigned short o[8];
    o[0] = f2bf((v0.x - mu) * rstd * g0.x + b0.x);
    o[1] = f2bf((v0.y - mu) * rstd * g0.y + b0.y);
    o[2] = f2bf((v0.z - mu) * rstd * g0.z + b0.z);
    o[3] = f2bf((v0.w - mu) * rstd * g0.w + b0.w);
    o[4] = f2bf((v1.x - mu) * rstd * g1.x + b1.x);
    o[5] = f2bf((v1.y - mu) * rstd * g1.y + b1.y);
    o[6] = f2bf((v1.z - mu) * rstd * g1.z + b1.z);
    o[7] = f2bf((v1.w - mu) * rstd * g1.w + b1.w);
    uint4 pk;
    pk.x = (unsigned)o[0] | ((unsigned)o[1] << 16);
    pk.y = (unsigned)o[2] | ((unsigned)o[3] << 16);
    pk.z = (unsigned)o[4] | ((unsigned)o[5] << 16);
    pk.w = (unsigned)o[6] | ((unsigned)o[7] << 16);
    *(uint4*)(nx + (size_t)row * C_DIM + tid * 8) = pk;
}

// ---------------- GEMM core: C[128x128] = A[128xK] * Bt[128xK]^T ------------
__device__ __forceinline__ void gemm_core(const unsigned short* __restrict__ A,
                                          const unsigned short* __restrict__ Bt,
                                          unsigned short* smA, unsigned short* smB,
                                          int rowBase, int colBase, f32x4 acc[4][4]) {
    const int tid = threadIdx.x;
    const int lane = tid & 63, wave = tid >> 6;
    const int quad = lane >> 4, lo = lane & 15;
    const int wrow = (wave >> 1) * 64, wcol = (wave & 1) * 64;
    for (int kt = 0; kt < C_DIM; kt += 32) {
        #pragma unroll
        for (int it = 0; it < 2; it++) {
            int u = it * 256 + tid;
            int r = u >> 2, c = u & 3;
            ((uint4*)smA)[u] = *(const uint4*)(A + (size_t)(rowBase + r) * C_DIM + kt + c * 8);
            ((uint4*)smB)[u] = *(const uint4*)(Bt + (size_t)(colBase + r) * C_DIM + kt + c * 8);
        }
        __syncthreads();
        short8 af[4], bf[4];
        #pragma unroll
        for (int mi = 0; mi < 4; mi++)
            af[mi] = *(const short8*)(smA + (wrow + mi * 16 + lo) * 32 + quad * 8);
        #pragma unroll
        for (int ni = 0; ni < 4; ni++)
            bf[ni] = *(const short8*)(smB + (wcol + ni * 16 + lo) * 32 + quad * 8);
        #pragma unroll
        for (int mi = 0; mi < 4; mi++)
            #pragma unroll
            for (int ni = 0; ni < 4; ni++)
                acc[mi][ni] = __builtin_amdgcn_mfma_f32_16x16x32_bf16(af[mi], bf[ni], acc[mi][ni], 0, 0, 0);
        __syncthreads();
    }
}

// ---------------- fused QKV GEMM (N = 6144) ---------------------------------
__global__ __launch_bounds__(256) void gemm_qkv(const unsigned short* __restrict__ A,
                                                const unsigned short* __restrict__ Bt,
                                                const float* __restrict__ bq,
                                                const float* __restrict__ bk,
                                                const float* __restrict__ bv,
                                                unsigned short* __restrict__ qb,
                                                unsigned short* __restrict__ kb,
                                                unsigned short* __restrict__ vtb) {
    __shared__ uint4 smAq[512];
    __shared__ uint4 smBq[512];
    f32x4 acc[4][4] = {};
    int rowBase = blockIdx.y * 128;
    int colBase = blockIdx.x * 128;
    gemm_core(A, Bt, (unsigned short*)smAq, (unsigned short*)smBq, rowBase, colBase, acc);

    const int lane = threadIdx.x & 63, wave = threadIdx.x >> 6;
    const int quad = lane >> 4, lo = lane & 15;
    const int wrow = (wave >> 1) * 64, wcol = (wave & 1) * 64;
    const int which = colBase >> 11;
    const float* bias = (which == 0) ? bq : (which == 1) ? bk : bv;
    #pragma unroll
    for (int mi = 0; mi < 4; mi++)
        #pragma unroll
        for (int ni = 0; ni < 4; ni++) {
            int n = colBase + wcol + ni * 16 + lo;
            int c = n & (C_DIM - 1), h = c >> 7, d = c & 127;
            float bsv = bias[c];
            #pragma unroll
            for (int r = 0; r < 4; r++) {
                int m = rowBase + wrow + mi * 16 + quad * 4 + r;
                int bb = m >> 11, t = m & (T_SEQ - 1);
                unsigned short u = f2bf(acc[mi][ni][r] + bsv);
                if (which == 2)
                    vtb[(size_t)((bb * H_NUM + h) * D_HEAD + d) * T_SEQ + t] = u;
                else if (which == 1)
                    kb[(size_t)((bb * H_NUM + h) * T_SEQ + t) * D_HEAD + d] = u;
                else
                    qb[(size_t)((bb * H_NUM + h) * T_SEQ + t) * D_HEAD + d] = u;
            }
        }
}

// ---------------- output GEMM + bias + residual -----------------------------
__global__ __launch_bounds__(256) void gemm_out(const unsigned short* __restrict__ A,
                                                const unsigned short* __restrict__ Bt,
                                                const float* __restrict__ bo,
                                                const float* __restrict__ x,
                                                float* __restrict__ out) {
    __shared__ uint4 smAq[512];
    __shared__ uint4 smBq[512];
    f32x4 acc[4][4] = {};
    int rowBase = blockIdx.y * 128;
    int colBase = blockIdx.x * 128;
    gemm_core(A, Bt, (unsigned short*)smAq, (unsigned short*)smBq, rowBase, colBase, acc);

    const int lane = threadIdx.x & 63, wave = threadIdx.x >> 6;
    const int quad = lane >> 4, lo = lane & 15;
    const int wrow = (wave >> 1) * 64, wcol = (wave & 1) * 64;
    #pragma unroll
    for (int mi = 0; mi < 4; mi++)
        #pragma unroll
        for (int ni = 0; ni < 4; ni++) {
            int n = colBase + wcol + ni * 16 + lo;
            float bsv = bo[n];
            #pragma unroll
            for (int r = 0; r < 4; r++) {
                int m = rowBase + wrow + mi * 16 + quad * 4 + r;
                size_t idx = (size_t)m * C_DIM + n;
                out[idx] = x[idx] + acc[mi][ni][r] + bsv;
            }
        }
}

// ---------------- RoPE (in-place on q or k, bf16) ---------------------------
__global__ __launch_bounds__(256) void rope_kernel(unsigned short* __restrict__ qb,
                                                   unsigned short* __restrict__ kb) {
    unsigned short* p = blockIdx.y ? kb : qb;
    int pidx = blockIdx.x * 256 + threadIdx.x;     // 0 .. B*H*T*64-1
    int dd = pidx & 63;
    int bht = pidx >> 6;
    int t = bht & (T_SEQ - 1);
    unsigned short* base = p + (size_t)bht * D_HEAD;
    float x0 = bf2f(base[dd]);
    float x1 = bf2f(base[dd + 64]);
    float inv = powf(10000.0f, -(float)dd * (1.0f / 64.0f));
    float ang = (float)t * inv;
    float sn, cs;
    sincosf(ang, &sn, &cs);
    base[dd]      = f2bf(x0 * cs - x1 * sn);
    base[dd + 64] = f2bf(x1 * cs + x0 * sn);
}

// ---------------- causal flash attention ------------------------------------
// one wave per 16-row Q tile; K tiles of 32; V pre-transposed [B,H,D,T]
__global__ __launch_bounds__(256) void attn_kernel(const unsigned short* __restrict__ q,
                                                   const unsigned short* __restrict__ k,
                                                   const unsigned short* __restrict__ vt,
                                                   unsigned short* __restrict__ attn_out) {
    __shared__ uint4 plds_q[4][64];                 // 16x32 bf16 P tile per wave
    const int lane = threadIdx.x & 63;
    const int wib = threadIdx.x >> 6;
    const int wid = blockIdx.x * 4 + wib;
    const int quad = lane >> 4, lo = lane & 15;
    const int head_lin = wid >> 7;                  // T/16 = 128 q-tiles per head
    const int qt = wid & 127;
    const int b = head_lin >> 4, h = head_lin & 15;
    const unsigned short* qbase = q + ((size_t)head_lin * T_SEQ + qt * 16) * D_HEAD;
    const unsigned short* kbase = k + (size_t)head_lin * T_SEQ * D_HEAD;
    const unsigned short* vbase = vt + (size_t)head_lin * D_HEAD * T_SEQ;
    unsigned short* plds = (unsigned short*)plds_q[wib];

    short8 qf[4];
    #pragma unroll
    for (int s2 = 0; s2 < 4; s2++)
        qf[s2] = *(const short8*)(qbase + lo * D_HEAD + s2 * 32 + quad * 8);

    float m_i[4], l_i[4];
    f32x4 o[8];
    #pragma unroll
    for (int r = 0; r < 4; r++) { m_i[r] = -1e30f; l_i[r] = 0.0f; }
    #pragma unroll
    for (int dt = 0; dt < 8; dt++) o[dt] = (f32x4){0.f, 0.f, 0.f, 0.f};

    const float scale = 0.08838834764831845f;       // 1/sqrt(128)
    const int tmax = qt * 16 + 15;
    const int nkt = tmax / 32 + 1;

    for (int kt = 0; kt < nkt; kt++) {
        f32x4 s_acc[2] = {(f32x4){0.f,0.f,0.f,0.f}, (f32x4){0.f,0.f,0.f,0.f}};
        #pragma unroll
        for (int nt = 0; nt < 2; nt++) {
            const unsigned short* kbp = kbase + (size_t)(kt * 32 + nt * 16 + lo) * D_HEAD;
            #pragma unroll
            for (int s2 = 0; s2 < 4; s2++) {
                short8 kf = *(const short8*)(kbp + s2 * 32 + quad * 8);
                s_acc[nt] = __builtin_amdgcn_mfma_f32_16x16x32_bf16(qf[s2], kf, s_acc[nt], 0, 0, 0);
            }
        }
        float alpha[4];
        int key0 = kt * 32 + lo, key1 = kt * 32 + 16 + lo;
        #pragma unroll
        for (int r = 0; r < 4; r++) {
            int tq = qt * 16 + quad * 4 + r;
            float s0 = (key0 <= tq) ? s_acc[0][r] * scale : -1e30f;
            float s1 = (key1 <= tq) ? s_acc[1][r] * scale : -1e30f;
            float mx = fmaxf(s0, s1);
            mx = fmaxf(mx, __shfl_xor(mx, 1));
            mx = fmaxf(mx, __shfl_xor(mx, 2));
            mx = fmaxf(mx, __shfl_xor(mx, 4));
            mx = fmaxf(mx, __shfl_xor(mx, 8));
            float mnew = fmaxf(m_i[r], mx);
            alpha[r] = expf(m_i[r] - mnew);
            float p0 = expf(s0 - mnew);
            float p1 = expf(s1 - mnew);
            float sm = p0 + p1;
            sm += __shfl_xor(sm, 1);
            sm += __shfl_xor(sm, 2);
            sm += __shfl_xor(sm, 4);
            sm += __shfl_xor(sm, 8);
            l_i[r] = l_i[r] * alpha[r] + sm;
            m_i[r] = mnew;
            plds[(quad * 4 + r) * 32 + lo] = f2bf(p0);
            plds[(quad * 4 + r) * 32 + 16 + lo] = f2bf(p1);
        }
        short8 pf = *(const short8*)(plds + lo * 32 + quad * 8);
        #pragma unroll
        for (int dt = 0; dt < 8; dt++) {
            short8 vf = *(const short8*)(vbase + (size_t)(dt * 16 + lo) * T_SEQ + kt * 32 + quad * 8);
            f32x4 oo = o[dt];
            #pragma unroll
            for (int r = 0; r < 4; r++) oo[r] *= alpha[r];
            o[dt] = __builtin_amdgcn_mfma_f32_16x16x32_bf16(pf, vf, oo, 0, 0, 0);
        }
    }

    float inv_l[4];
    #pragma unroll
    for (int r = 0; r < 4; r++) inv_l[r] = 1.0f / l_i[r];
    const size_t bT = (size_t)b * T_SEQ;
    #pragma unroll
    for (int dt = 0; dt < 8; dt++)
        #pragma unroll
        for (int r = 0; r < 4; r++) {
            int t = qt * 16 + quad * 4 + r;
            attn_out[(bT + t) * C_DIM + h * D_HEAD + dt * 16 + lo] = f2bf(o[dt][r] * inv_l[r]);
        }
}

// ---------------- launch -----------------------------------------------------
extern "C" void kernel_launch(void* const* d_in, const int* in_sizes, int n_in,
                              void* d_out, int out_size, void* d_ws, size_t ws_size,
                              hipStream_t stream) {
    const float* x    = (const float*)d_in[0];
    const float* ln_g = (const float*)d_in[1];
    const float* ln_b = (const float*)d_in[2];
    const float* Wq   = (const float*)d_in[3];
    const float* bq   = (const float*)d_in[4];
    const float* Wk   = (const float*)d_in[5];
    const float* bk   = (const float*)d_in[6];
    const float* Wv   = (const float*)d_in[7];
    const float* bv   = (const float*)d_in[8];
    const float* Wo   = (const float*)d_in[9];
    const float* bo   = (const float*)d_in[10];
    float* out = (float*)d_out;

    char* ws = (char*)d_ws;
    const size_t SZ = (size_t)M_ROWS * C_DIM * 2;        // 33,554,432 bytes
    unsigned short* nx  = (unsigned short*)(ws);
    unsigned short* wt  = (unsigned short*)(ws + SZ);    // 4 x 2048 x 2048 bf16
    unsigned short* qb  = (unsigned short*)(ws + 2 * SZ);
    unsigned short* kb  = (unsigned short*)(ws + 3 * SZ);
    unsigned short* vtb = (unsigned short*)(ws + 4 * SZ);
    unsigned short* at  = (unsigned short*)(ws + 5 * SZ);

    wcast_kernel<<<dim3(64, 64, 4), dim3(32, 8), 0, stream>>>(Wq, Wk, Wv, Wo, wt);
    ln_kernel<<<M_ROWS, 256, 0, stream>>>(x, ln_g, ln_b, nx);
    gemm_qkv<<<dim3(48, 64), 256, 0, stream>>>(nx, wt, bq, bk, bv, qb, kb, vtb);
    rope_kernel<<<dim3((B_NUM * H_NUM * T_SEQ * 64) / 256, 2), 256, 0, stream>>>(qb, kb);
    attn_kernel<<<2048, 256, 0, stream>>>(qb, kb, vtb, at);
    gemm_out<<<dim3(16, 64), 256, 0, stream>>>(at, wt + (size_t)3 * C_DIM * C_DIM, bo, x, out);
}

// Round 2
// 1338.280 us; speedup vs baseline: 1.1494x; 1.1494x over previous
//
#include <hip/hip_runtime.h>

typedef short short8 __attribute__((ext_vector_type(8)));
typedef float f32x4 __attribute__((ext_vector_type(4)));

#define T_SEQ 2048
#define C_DIM 2048
#define H_NUM 16
#define D_HEAD 128
#define B_NUM 4
#define M_ROWS (B_NUM * T_SEQ)   // 8192
#define PPAD 72                  // P-tile LDS row stride (2-way bank alias = free)

__device__ __forceinline__ unsigned short f2bf(float f) {
    union { float f; unsigned u; } v; v.f = f;
    unsigned r = v.u + 0x7FFFu + ((v.u >> 16) & 1u);
    return (unsigned short)(r >> 16);
}
__device__ __forceinline__ float bf2f(unsigned short u) {
    union { unsigned u; float f; } v; v.u = ((unsigned)u) << 16;
    return v.f;
}

// async global->LDS, 16B per lane; lds ptr must be wave-uniform (HW adds lane*16)
__device__ __forceinline__ void async_ld16(const unsigned short* g, unsigned short* l) {
    __builtin_amdgcn_global_load_lds(
        (const __attribute__((address_space(1))) unsigned int*)g,
        (__attribute__((address_space(3))) unsigned int*)l,
        16, 0, 0);
}

// ---------------- weight cast + transpose: wt[w][n][k] = W_w[k][n] (bf16) ----
__global__ __launch_bounds__(256) void wcast_kernel(const float* __restrict__ W0,
                                                    const float* __restrict__ W1,
                                                    const float* __restrict__ W2,
                                                    const float* __restrict__ W3,
                                                    unsigned short* __restrict__ wt) {
    __shared__ float tile[32][33];
    const float* W = (blockIdx.z == 0) ? W0 : (blockIdx.z == 1) ? W1 : (blockIdx.z == 2) ? W2 : W3;
    unsigned short* out = wt + (size_t)blockIdx.z * C_DIM * C_DIM;
    int tx = threadIdx.x, ty = threadIdx.y;      // block (32, 8)
    int n0 = blockIdx.x * 32, k0 = blockIdx.y * 32;
    #pragma unroll
    for (int j = 0; j < 32; j += 8)
        tile[ty + j][tx] = W[(size_t)(k0 + ty + j) * C_DIM + n0 + tx];
    __syncthreads();
    #pragma unroll
    for (int j = 0; j < 32; j += 8)
        out[(size_t)(n0 + ty + j) * C_DIM + k0 + tx] = f2bf(tile[tx][ty + j]);
}

// ---------------- LayerNorm -> bf16 ----------------------------------------
__global__ __launch_bounds__(256) void ln_kernel(const float* __restrict__ x,
                                                 const float* __restrict__ g,
                                                 const float* __restrict__ bta,
                                                 unsigned short* __restrict__ nx) {
    int row = blockIdx.x;
    int tid = threadIdx.x;
    const float* xr = x + (size_t)row * C_DIM;
    float4 v0 = *(const float4*)(xr + tid * 8);
    float4 v1 = *(const float4*)(xr + tid * 8 + 4);
    float s = v0.x + v0.y + v0.z + v0.w + v1.x + v1.y + v1.z + v1.w;
    float q = v0.x * v0.x + v0.y * v0.y + v0.z * v0.z + v0.w * v0.w +
              v1.x * v1.x + v1.y * v1.y + v1.z * v1.z + v1.w * v1.w;
    #pragma unroll
    for (int m = 32; m; m >>= 1) { s += __shfl_xor(s, m); q += __shfl_xor(q, m); }
    __shared__ float red[2][4];
    int wave = tid >> 6, lane = tid & 63;
    if (lane == 0) { red[0][wave] = s; red[1][wave] = q; }
    __syncthreads();
    s = red[0][0] + red[0][1] + red[0][2] + red[0][3];
    q = red[1][0] + red[1][1] + red[1][2] + red[1][3];
    float mu = s * (1.0f / C_DIM);
    float var = q * (1.0f / C_DIM) - mu * mu;
    float rstd = rsqrtf(var + 1e-5f);
    float4 g0 = *(const float4*)(g + tid * 8);
    float4 g1 = *(const float4*)(g + tid * 8 + 4);
    float4 b0 = *(const float4*)(bta + tid * 8);
    float4 b1 = *(const float4*)(bta + tid * 8 + 4);
    unsigned short o[8];
    o[0] = f2bf((v0.x - mu) * rstd * g0.x + b0.x);
    o[1] = f2bf((v0.y - mu) * rstd * g0.y + b0.y);
    o[2] = f2bf((v0.z - mu) * rstd * g0.z + b0.z);
    o[3] = f2bf((v0.w - mu) * rstd * g0.w + b0.w);
    o[4] = f2bf((v1.x - mu) * rstd * g1.x + b1.x);
    o[5] = f2bf((v1.y - mu) * rstd * g1.y + b1.y);
    o[6] = f2bf((v1.z - mu) * rstd * g1.z + b1.z);
    o[7] = f2bf((v1.w - mu) * rstd * g1.w + b1.w);
    uint4 pk;
    pk.x = (unsigned)o[0] | ((unsigned)o[1] << 16);
    pk.y = (unsigned)o[2] | ((unsigned)o[3] << 16);
    pk.z = (unsigned)o[4] | ((unsigned)o[5] << 16);
    pk.w = (unsigned)o[6] | ((unsigned)o[7] << 16);
    *(uint4*)(nx + (size_t)row * C_DIM + tid * 8) = pk;
}

// ---------------- GEMM core: C[128x128] = A[128xK] * Bt[128xK]^T ------------
// global_load_lds width=16 staging (m97 pattern): LDS layout is exactly
// lane-order contiguous, so pass the wave-uniform base and let HW scatter.
__device__ __forceinline__ void gemm_core(const unsigned short* __restrict__ A,
                                          const unsigned short* __restrict__ Bt,
                                          unsigned short* smA, unsigned short* smB,
                                          int rowBase, int colBase, f32x4 acc[4][4]) {
    const int tid = threadIdx.x;
    const int lane = tid & 63, wave = tid >> 6;
    const int quad = lane >> 4, lo = lane & 15;
    const int wrow = (wave >> 1) * 64, wcol = (wave & 1) * 64;
    for (int kt = 0; kt < C_DIM; kt += 32) {
        #pragma unroll
        for (int it = 0; it < 2; it++) {
            int ubase = it * 256 + wave * 64;      // wave-uniform LDS chunk base
            int u = ubase + lane;
            int r = u >> 2, c = u & 3;
            async_ld16(A + (size_t)(rowBase + r) * C_DIM + kt + c * 8, smA + (size_t)ubase * 8);
            async_ld16(Bt + (size_t)(colBase + r) * C_DIM + kt + c * 8, smB + (size_t)ubase * 8);
        }
        __syncthreads();
        short8 af[4], bf[4];
        #pragma unroll
        for (int mi = 0; mi < 4; mi++)
            af[mi] = *(const short8*)(smA + (wrow + mi * 16 + lo) * 32 + quad * 8);
        #pragma unroll
        for (int ni = 0; ni < 4; ni++)
            bf[ni] = *(const short8*)(smB + (wcol + ni * 16 + lo) * 32 + quad * 8);
        #pragma unroll
        for (int mi = 0; mi < 4; mi++)
            #pragma unroll
            for (int ni = 0; ni < 4; ni++)
                acc[mi][ni] = __builtin_amdgcn_mfma_f32_16x16x32_bf16(af[mi], bf[ni], acc[mi][ni], 0, 0, 0);
        __syncthreads();
    }
}

// ---------------- fused QKV GEMM (N = 6144) ---------------------------------
__global__ __launch_bounds__(256) void gemm_qkv(const unsigned short* __restrict__ A,
                                                const unsigned short* __restrict__ Bt,
                                                const float* __restrict__ bq,
                                                const float* __restrict__ bk,
                                                const float* __restrict__ bv,
                                                unsigned short* __restrict__ qb,
                                                unsigned short* __restrict__ kb,
                                                unsigned short* __restrict__ vtb) {
    __shared__ uint4 smAq[512];
    __shared__ uint4 smBq[512];
    f32x4 acc[4][4] = {};
    int rowBase = blockIdx.y * 128;
    int colBase = blockIdx.x * 128;
    gemm_core(A, Bt, (unsigned short*)smAq, (unsigned short*)smBq, rowBase, colBase, acc);

    const int lane = threadIdx.x & 63, wave = threadIdx.x >> 6;
    const int quad = lane >> 4, lo = lane & 15;
    const int wrow = (wave >> 1) * 64, wcol = (wave & 1) * 64;
    const int which = colBase >> 11;
    const float* bias = (which == 0) ? bq : (which == 1) ? bk : bv;
    #pragma unroll
    for (int mi = 0; mi < 4; mi++)
        #pragma unroll
        for (int ni = 0; ni < 4; ni++) {
            int n = colBase + wcol + ni * 16 + lo;
            int c = n & (C_DIM - 1), h = c >> 7, d = c & 127;
            float bsv = bias[c];
            #pragma unroll
            for (int r = 0; r < 4; r++) {
                int m = rowBase + wrow + mi * 16 + quad * 4 + r;
                int bb = m >> 11, t = m & (T_SEQ - 1);
                unsigned short u = f2bf(acc[mi][ni][r] + bsv);
                if (which == 2)
                    vtb[(size_t)((bb * H_NUM + h) * D_HEAD + d) * T_SEQ + t] = u;
                else if (which == 1)
                    kb[(size_t)((bb * H_NUM + h) * T_SEQ + t) * D_HEAD + d] = u;
                else
                    qb[(size_t)((bb * H_NUM + h) * T_SEQ + t) * D_HEAD + d] = u;
            }
        }
}

// ---------------- output GEMM + bias + residual -----------------------------
__global__ __launch_bounds__(256) void gemm_out(const unsigned short* __restrict__ A,
                                                const unsigned short* __restrict__ Bt,
                                                const float* __restrict__ bo,
                                                const float* __restrict__ x,
                                                float* __restrict__ out) {
    __shared__ uint4 smAq[512];
    __shared__ uint4 smBq[512];
    f32x4 acc[4][4] = {};
    int rowBase = blockIdx.y * 128;
    int colBase = blockIdx.x * 128;
    gemm_core(A, Bt, (unsigned short*)smAq, (unsigned short*)smBq, rowBase, colBase, acc);

    const int lane = threadIdx.x & 63, wave = threadIdx.x >> 6;
    const int quad = lane >> 4, lo = lane & 15;
    const int wrow = (wave >> 1) * 64, wcol = (wave & 1) * 64;
    #pragma unroll
    for (int mi = 0; mi < 4; mi++)
        #pragma unroll
        for (int ni = 0; ni < 4; ni++) {
            int n = colBase + wcol + ni * 16 + lo;
            float bsv = bo[n];
            #pragma unroll
            for (int r = 0; r < 4; r++) {
                int m = rowBase + wrow + mi * 16 + quad * 4 + r;
                size_t idx = (size_t)m * C_DIM + n;
                out[idx] = x[idx] + acc[mi][ni][r] + bsv;
            }
        }
}

// ---------------- RoPE (in-place, bf16); folds 1/sqrt(D) into Q -------------
__global__ __launch_bounds__(256) void rope_kernel(unsigned short* __restrict__ qb,
                                                   unsigned short* __restrict__ kb) {
    const bool isk = (blockIdx.y != 0);
    unsigned short* p = isk ? kb : qb;
    const float osc = isk ? 1.0f : 0.08838834764831845f;   // 1/sqrt(128) folded into Q
    int pidx = blockIdx.x * 256 + threadIdx.x;     // 0 .. B*H*T*64-1
    int dd = pidx & 63;
    int bht = pidx >> 6;
    int t = bht & (T_SEQ - 1);
    unsigned short* base = p + (size_t)bht * D_HEAD;
    float x0 = bf2f(base[dd]);
    float x1 = bf2f(base[dd + 64]);
    float inv = exp2f((float)dd * (-13.287712379549449f / 64.0f));  // 10000^(-dd/64)
    float ang = (float)t * inv;
    float sn = __sinf(ang), cs = __cosf(ang);
    base[dd]      = f2bf((x0 * cs - x1 * sn) * osc);
    base[dd + 64] = f2bf((x1 * cs + x0 * sn) * osc);
}

// ---------------- causal flash attention ------------------------------------
// One wave per 16-row Q tile; K-tile = 64 keys; each wave processes the tile
// PAIR (qt, 127-qt) -> constant work per wave (perfect balance); grid = 1024
// blocks = 4 blocks/CU fully co-resident. Q pre-scaled by 1/sqrt(D) in rope.
__device__ __forceinline__ void attn_tile(const unsigned short* __restrict__ qh,
                                          const unsigned short* __restrict__ kh,
                                          const unsigned short* __restrict__ vh,
                                          unsigned short* __restrict__ attn_out,
                                          int qt, int b, int h, int quad, int lo,
                                          unsigned short* plds) {
    short8 qf[4];
    #pragma unroll
    for (int s2 = 0; s2 < 4; s2++)
        qf[s2] = *(const short8*)(qh + (size_t)(qt * 16 + lo) * D_HEAD + s2 * 32 + quad * 8);

    float m_i[4], l_i[4];
    f32x4 o[8];
    #pragma unroll
    for (int r = 0; r < 4; r++) { m_i[r] = -1e30f; l_i[r] = 0.0f; }
    #pragma unroll
    for (int dt = 0; dt < 8; dt++) o[dt] = (f32x4){0.f, 0.f, 0.f, 0.f};

    const int nfull = qt >> 2;                       // mask-free 64-key tiles
    const int nkt = ((qt * 16 + 15) >> 6) + 1;

    for (int kt = 0; kt < nkt; kt++) {
        const bool masked = (kt >= nfull);           // wave-uniform branch
        f32x4 s_acc[4] = {(f32x4){0.f,0.f,0.f,0.f}, (f32x4){0.f,0.f,0.f,0.f},
                          (f32x4){0.f,0.f,0.f,0.f}, (f32x4){0.f,0.f,0.f,0.f}};
        const unsigned short* kbp = kh + (size_t)(kt * 64) * D_HEAD;
        #pragma unroll
        for (int nt = 0; nt < 4; nt++)
            #pragma unroll
            for (int s2 = 0; s2 < 4; s2++) {
                short8 kf = *(const short8*)(kbp + (size_t)(nt * 16 + lo) * D_HEAD + s2 * 32 + quad * 8);
                s_acc[nt] = __builtin_amdgcn_mfma_f32_16x16x32_bf16(qf[s2], kf, s_acc[nt], 0, 0, 0);
            }
        float alpha[4];
        #pragma unroll
        for (int r = 0; r < 4; r++) {
            int tq = qt * 16 + quad * 4 + r;
            float s0 = s_acc[0][r], s1 = s_acc[1][r], s2v = s_acc[2][r], s3 = s_acc[3][r];
            if (masked) {
                int key = kt * 64 + lo;
                s0  = (key      <= tq) ? s0  : -1e30f;
                s1  = (key + 16 <= tq) ? s1  : -1e30f;
                s2v = (key + 32 <= tq) ? s2v : -1e30f;
                s3  = (key + 48 <= tq) ? s3  : -1e30f;
            }
            float mx = fmaxf(fmaxf(s0, s1), fmaxf(s2v, s3));
            mx = fmaxf(mx, __shfl_xor(mx, 1));
            mx = fmaxf(mx, __shfl_xor(mx, 2));
            mx = fmaxf(mx, __shfl_xor(mx, 4));
            mx = fmaxf(mx, __shfl_xor(mx, 8));
            float mnew = fmaxf(m_i[r], mx);
            alpha[r] = __expf(m_i[r] - mnew);
            float p0 = __expf(s0 - mnew);
            float p1 = __expf(s1 - mnew);
            float p2 = __expf(s2v - mnew);
            float p3 = __expf(s3 - mnew);
            float sm = (p0 + p1) + (p2 + p3);
            sm += __shfl_xor(sm, 1);
            sm += __shfl_xor(sm, 2);
            sm += __shfl_xor(sm, 4);
            sm += __shfl_xor(sm, 8);
            l_i[r] = l_i[r] * alpha[r] + sm;
            m_i[r] = mnew;
            int prow = (quad * 4 + r) * PPAD;
            plds[prow + lo]      = f2bf(p0);
            plds[prow + 16 + lo] = f2bf(p1);
            plds[prow + 32 + lo] = f2bf(p2);
            plds[prow + 48 + lo] = f2bf(p3);
        }
        // P (C-layout) -> A-fragment layout, same-wave LDS round trip
        short8 pf0 = *(const short8*)(plds + lo * PPAD + quad * 8);
        short8 pf1 = *(const short8*)(plds + lo * PPAD + 32 + quad * 8);
        #pragma unroll
        for (int dt = 0; dt < 8; dt++) {
            const unsigned short* vr = vh + (size_t)(dt * 16 + lo) * T_SEQ + kt * 64;
            short8 vf0 = *(const short8*)(vr + quad * 8);
            short8 vf1 = *(const short8*)(vr + 32 + quad * 8);
            f32x4 oo = o[dt];
            #pragma unroll
            for (int r = 0; r < 4; r++) oo[r] *= alpha[r];
            oo = __builtin_amdgcn_mfma_f32_16x16x32_bf16(pf0, vf0, oo, 0, 0, 0);
            oo = __builtin_amdgcn_mfma_f32_16x16x32_bf16(pf1, vf1, oo, 0, 0, 0);
            o[dt] = oo;
        }
    }

    float inv_l[4];
    #pragma unroll
    for (int r = 0; r < 4; r++) inv_l[r] = 1.0f / l_i[r];
    const size_t bT = (size_t)b * T_SEQ;
    #pragma unroll
    for (int dt = 0; dt < 8; dt++)
        #pragma unroll
        for (int r = 0; r < 4; r++) {
            int t = qt * 16 + quad * 4 + r;
            attn_out[(bT + t) * C_DIM + h * D_HEAD + dt * 16 + lo] = f2bf(o[dt][r] * inv_l[r]);
        }
}

__global__ __launch_bounds__(256) void attn_kernel(const unsigned short* __restrict__ q,
                                                   const unsigned short* __restrict__ k,
                                                   const unsigned short* __restrict__ vt,
                                                   unsigned short* __restrict__ attn_out) {
    __shared__ unsigned short plds_all[4][16 * PPAD];
    const int lane = threadIdx.x & 63;
    const int wib = threadIdx.x >> 6;
    const int wid = blockIdx.x * 4 + wib;           // 0..4095
    const int head_lin = wid >> 6;                  // 0..63 (b*16+h)
    const int pr = wid & 63;                        // pair index
    const int quad = lane >> 4, lo = lane & 15;
    const int b = head_lin >> 4, h = head_lin & 15;
    const unsigned short* qh = q + (size_t)head_lin * T_SEQ * D_HEAD;
    const unsigned short* kh = k + (size_t)head_lin * T_SEQ * D_HEAD;
    const unsigned short* vh = vt + (size_t)head_lin * D_HEAD * T_SEQ;
    unsigned short* plds = plds_all[wib];

    attn_tile(qh, kh, vh, attn_out, pr, b, h, quad, lo, plds);        // light tile
    attn_tile(qh, kh, vh, attn_out, 127 - pr, b, h, quad, lo, plds);  // heavy tile
}

// ---------------- launch -----------------------------------------------------
extern "C" void kernel_launch(void* const* d_in, const int* in_sizes, int n_in,
                              void* d_out, int out_size, void* d_ws, size_t ws_size,
                              hipStream_t stream) {
    const float* x    = (const float*)d_in[0];
    const float* ln_g = (const float*)d_in[1];
    const float* ln_b = (const float*)d_in[2];
    const float* Wq   = (const float*)d_in[3];
    const float* bq   = (const float*)d_in[4];
    const float* Wk   = (const float*)d_in[5];
    const float* bk   = (const float*)d_in[6];
    const float* Wv   = (const float*)d_in[7];
    const float* bv   = (const float*)d_in[8];
    const float* Wo   = (const float*)d_in[9];
    const float* bo   = (const float*)d_in[10];
    float* out = (float*)d_out;

    char* ws = (char*)d_ws;
    const size_t SZ = (size_t)M_ROWS * C_DIM * 2;        // 33,554,432 bytes
    unsigned short* nx  = (unsigned short*)(ws);
    unsigned short* wt  = (unsigned short*)(ws + SZ);    // 4 x 2048 x 2048 bf16
    unsigned short* qb  = (unsigned short*)(ws + 2 * SZ);
    unsigned short* kb  = (unsigned short*)(ws + 3 * SZ);
    unsigned short* vtb = (unsigned short*)(ws + 4 * SZ);
    unsigned short* at  = (unsigned short*)(ws + 5 * SZ);

    wcast_kernel<<<dim3(64, 64, 4), dim3(32, 8), 0, stream>>>(Wq, Wk, Wv, Wo, wt);
    ln_kernel<<<M_ROWS, 256, 0, stream>>>(x, ln_g, ln_b, nx);
    gemm_qkv<<<dim3(48, 64), 256, 0, stream>>>(nx, wt, bq, bk, bv, qb, kb, vtb);
    rope_kernel<<<dim3((B_NUM * H_NUM * T_SEQ * 64) / 256, 2), 256, 0, stream>>>(qb, kb);
    attn_kernel<<<1024, 256, 0, stream>>>(qb, kb, vtb, at);
    gemm_out<<<dim3(16, 64), 256, 0, stream>>>(at, wt + (size_t)3 * C_DIM * C_DIM, bo, x, out);
}